// Round 13
// baseline (136.793 us; speedup 1.0000x reference)
//
#include <hip/hip_runtime.h>
#include <hip/hip_bf16.h>
#include <math.h>

// FeedForwardQuantum — Round 19: resubmission of Round 18 (container infra
// failure, kernel never ran). BARRIER-FREE fused kernel:
// each wave produces h for ITS OWN 64 output rows (2x h-MFMA duplication)
// into a WAVE-PRIVATE LDS region -> no cross-wave dependency -> zero
// barriers in the main loop (one after Z-prologue). Waves free-run on
// compiler-inserted per-wave counted waitcnts. B via pre-swizzled w2p,
// w1t frags prefetched per-chunk. Swizzle pair / MFMA order / epilogue
// verbatim harness-verified rounds -> bit-identical output (absmax 0.00390625).

typedef __attribute__((ext_vector_type(8))) short short8;
typedef __attribute__((ext_vector_type(8))) unsigned short ushort8;
typedef __attribute__((ext_vector_type(4))) float fx4;

constexpr int EDIM = 512;
constexpr int FDIM = 2048;
constexpr int NQ   = 10;
constexpr int BK   = 64;
constexpr int BM   = 128;
constexpr int BN   = 128;
constexpr int CSTR = 8192;        // w2p elements per chunk (per ng)
constexpr int NGSTR = 262144;     // w2p elements per ng (32 chunks)
constexpr int W2P_UNITS = EDIM * FDIM / 8;   // 131072

__device__ __forceinline__ ushort f2bf(float f) {   // f32 -> bf16 RNE
    union { float f; unsigned u; } v; v.f = f;
    unsigned u = v.u + 0x7FFFu + ((v.u >> 16) & 1u);
    return (ushort)(u >> 16);
}
__device__ __forceinline__ float bf2f(ushort u) {
    union { unsigned u; float f; } v; v.u = (unsigned)u << 16; return v.f;
}
// HW packed f32x2 -> bf16x2, RNE (bit-identical to manual f2bf pair)
__device__ __forceinline__ unsigned cvtpk(float lo, float hi) {
    unsigned r;
    asm("v_cvt_pk_bf16_f32 %0, %1, %2" : "=v"(r) : "v"(lo), "v"(hi));
    return r;
}

// ---- prep: w2 -> w2p (fragment-ordered) + split-precision w1t ----
__global__ void prep(const float* __restrict__ w2, const float* __restrict__ w1,
                     const float* __restrict__ b1,
                     ushort* __restrict__ w2p, ushort* __restrict__ w1t) {
    int gid = blockIdx.x * blockDim.x + threadIdx.x;
    int np  = gridDim.x * blockDim.x;
    for (int u = gid; u < W2P_UNITS; u += np) {
        int l16 = u & 15, quad = (u >> 4) & 3, hf = (u >> 6) & 1;
        int nt = (u >> 7) & 3, wn = (u >> 9) & 1, c = (u >> 10) & 31, ng = u >> 15;
        int row = ng * 128 + wn * 64 + nt * 16 + l16;
        int col = c * 64 + (hf * 4 + quad) * 8;
        const float* src = w2 + (size_t)row * FDIM + col;
        float4 a = *(const float4*)src;
        float4 b = *(const float4*)(src + 4);
        ushort8 o;
        o[0] = f2bf(a.x); o[1] = f2bf(a.y); o[2] = f2bf(a.z); o[3] = f2bf(a.w);
        o[4] = f2bf(b.x); o[5] = f2bf(b.y); o[6] = f2bf(b.z); o[7] = f2bf(b.w);
        *(ushort8*)&w2p[(size_t)u * 8] = o;
    }
    for (int f = gid; f < FDIM; f += np) {
        ushort zr[32];
        #pragma unroll
        for (int w = 0; w < NQ; ++w) {
            float v  = w1[f * NQ + w];
            ushort hb = f2bf(v);
            ushort lb = f2bf(v - bf2f(hb));
            zr[w] = hb; zr[10 + w] = hb; zr[20 + w] = lb;
        }
        float bv  = b1[f];
        ushort bh = f2bf(bv);
        zr[30] = bh; zr[31] = f2bf(bv - bf2f(bh));
        #pragma unroll
        for (int u = 0; u < 4; ++u)
            *(ushort8*)&w1t[f * 32 + u * 8] = *(ushort8*)&zr[u * 8];
    }
}

// ---- fused: out = relu(q@w1^T+b1) @ w2^T + b2 — no main-loop barriers ----
__global__ __launch_bounds__(256, 2) void fused(
    const float* __restrict__ x, const float* __restrict__ rx,
    const ushort* __restrict__ w1t,   // [FDIM][32] bf16 split-precision
    const ushort* __restrict__ w2p,   // fragment-ordered w2 bf16
    const float* __restrict__ b2,
    float* __restrict__ out)
{
    __shared__ __align__(16) ushort Zs[BM * 32];      // 8 KiB
    __shared__ __align__(16) ushort As[2 * 4 * 4096]; // 64 KiB: [buf][wave][64*64]

    const int tid = threadIdx.x;
    const int m0  = blockIdx.x * BM;
    const int n0  = blockIdx.y * BN;

    // ---- q prologue (verbatim) -> split bf16 Z rows ----
    if (tid < BM) {
        const float* xr = x + (size_t)(m0 + tid) * EDIM;
        float4 xa = *(const float4*)xr;
        float4 xb = *(const float4*)(xr + 4);
        float2 xc = *(const float2*)(xr + 8);
        float xv[NQ] = {xa.x, xa.y, xa.z, xa.w, xb.x, xb.y, xb.z, xb.w, xc.x, xc.y};
        float c[NQ], q[NQ];
        #pragma unroll
        for (int w = 0; w < NQ; ++w) c[w] = cosf(xv[w] + rx[w]);
        float p0 = c[1];
        #pragma unroll
        for (int w = 2; w < NQ; ++w) p0 *= c[w];
        q[0] = p0;
        float p = c[0];
        #pragma unroll
        for (int w = 1; w < NQ; ++w) { p *= c[w]; q[w] = p; }
        ushort zr[32];
        #pragma unroll
        for (int w = 0; w < NQ; ++w) {
            ushort hb = f2bf(q[w]);
            ushort lb = f2bf(q[w] - bf2f(hb));
            zr[w] = hb; zr[10 + w] = lb; zr[20 + w] = hb;
        }
        zr[30] = 0x3F80u; zr[31] = 0x3F80u;   // 1.0, 1.0
        #pragma unroll
        for (int u = 0; u < 4; ++u)
            *(ushort8*)&Zs[tid * 32 + u * 8] = *(ushort8*)&zr[u * 8];
    }
    __syncthreads();     // the ONLY block-wide barrier

    const int wave = tid >> 6, lane = tid & 63;
    const int quad = lane >> 4, l16 = lane & 15;
    const int wm   = wave >> 1, wn = wave & 1;
    const int swz  = l16 & 7;

    // wave-private h: this wave produces h for rows wm*64..+63, ALL 64 f/chunk
    short8 zf[4];
    #pragma unroll
    for (int mi = 0; mi < 4; ++mi)
        zf[mi] = *(const short8*)&Zs[(wm * 64 + mi * 16 + l16) * 32 + quad * 8];

    // B: coalesced frag loads from pre-swizzled w2p (L2-resident)
    const ushort* gB = w2p + (size_t)blockIdx.y * NGSTR + wn * 4096 + lane * 8;
    // w1t frag pointer (advances 2048 elems = 64 f per chunk)
    const ushort* gW = w1t + l16 * 32 + quad * 8;

    // A fragment-read offsets within the wave-private 64x64 region
    int aro[4];
    #pragma unroll
    for (int t = 0; t < 4; ++t)
        aro[t] = (t * 16 + l16) * BK;
    ushort* wavebuf0 = &As[(0 * 4 + wave) * 4096];
    ushort* wavebuf1 = &As[(1 * 4 + wave) * 4096];

    fx4 acc[4][4];
    #pragma unroll
    for (int a = 0; a < 4; ++a)
        #pragma unroll
        for (int b = 0; b < 4; ++b) acc[a][b] = fx4{0.f, 0.f, 0.f, 0.f};

    const fx4 zacc = fx4{0.f, 0.f, 0.f, 0.f};

    short8 wfE[4], wfO[4];
    short8 bfE[4][2], bfO[4][2];

#define WLOAD(WF) do { _Pragma("unroll") \
    for (int fi = 0; fi < 4; ++fi) WF[fi] = *(const short8*)(gW + fi * 512); \
    gW += 2048; \
} while (0)

#define BLOAD(BFR) do { _Pragma("unroll") \
    for (int nt = 0; nt < 4; ++nt) { \
        BFR[nt][0] = *(const short8*)(gB + nt * 1024); \
        BFR[nt][1] = *(const short8*)(gB + nt * 1024 + 512); \
    } \
    gB += CSTR; \
} while (0)

// h-produce one chunk (16 MFMA, per-fi group) into wave-private WB
#define HPROD(WB, WF) do { _Pragma("unroll") \
    for (int fi = 0; fi < 4; ++fi) { \
        fx4 hv[4]; \
        _Pragma("unroll") \
        for (int mi = 0; mi < 4; ++mi) \
            hv[mi] = __builtin_amdgcn_mfma_f32_16x16x32_bf16( \
                WF[fi], zf[mi], zacc, 0, 0, 0); \
        _Pragma("unroll") \
        for (int mi = 0; mi < 4; ++mi) { \
            unsigned ua = cvtpk(fmaxf(hv[mi][0], 0.f), fmaxf(hv[mi][1], 0.f)); \
            unsigned ub = cvtpk(fmaxf(hv[mi][2], 0.f), fmaxf(hv[mi][3], 0.f)); \
            const int blk = fi * 2 + (quad >> 1); \
            *(uint2*)&(WB)[(mi * 16 + l16) * BK + ((blk ^ swz) << 3) + ((quad & 1) << 2)] \
                = make_uint2(ua, ub); \
        } \
    } \
} while (0)

// A from wave-private LDS, B from registers; MFMA order verbatim
#define COMPUTE(RB, BFR) do { \
    short8 af[4][2]; \
    _Pragma("unroll") \
    for (int t = 0; t < 4; ++t) \
        _Pragma("unroll") \
        for (int hf = 0; hf < 2; ++hf) \
            af[t][hf] = *(const short8*)&(RB)[aro[t] + (((hf * 4 + quad) ^ swz) << 3)]; \
    __builtin_amdgcn_s_setprio(1); \
    _Pragma("unroll") \
    for (int hf = 0; hf < 2; ++hf) \
        _Pragma("unroll") \
        for (int mt = 0; mt < 4; ++mt) \
            _Pragma("unroll") \
            for (int nt = 0; nt < 4; ++nt) \
                acc[mt][nt] = __builtin_amdgcn_mfma_f32_16x16x32_bf16( \
                    af[mt][hf], BFR[nt][hf], acc[mt][nt], 0, 0, 0); \
    __builtin_amdgcn_s_setprio(0); \
} while (0)

    // ---- wave-local prologue: h(0)->buf0, h(1)->buf1, B(0), B(1) ----
    WLOAD(wfE); BLOAD(bfE);           // chunk 0
    HPROD(wavebuf0, wfE);
    WLOAD(wfO); BLOAD(bfO);           // chunk 1
    HPROD(wavebuf1, wfO);

    // ---- main loop: 15 uniform pairs; chunk i in buf i&1; NO barriers ----
    for (int p = 0; p < 15; ++p) {
        WLOAD(wfE);                   // w1t frags for chunk 2p+2
        COMPUTE(wavebuf0, bfE);       // chunk 2p
        BLOAD(bfE);                   // B for chunk 2p+2 (after bfE consumed)
        HPROD(wavebuf0, wfE);         // h(2p+2) (after buf0 reads retired)
        WLOAD(wfO);                   // chunk 2p+3
        COMPUTE(wavebuf1, bfO);       // chunk 2p+1
        BLOAD(bfO);                   // B for chunk 2p+3
        HPROD(wavebuf1, wfO);         // h(2p+3)
    }
    // ---- tail: chunks 30, 31 ----
    COMPUTE(wavebuf0, bfE);
    COMPUTE(wavebuf1, bfO);

#undef COMPUTE
#undef HPROD
#undef BLOAD
#undef WLOAD

    // ---- epilogue: + b2 (verbatim, harness-verified layout) ----
    float bb[4];
    #pragma unroll
    for (int nt = 0; nt < 4; ++nt) bb[nt] = b2[n0 + wn * 64 + nt * 16 + l16];
    #pragma unroll
    for (int mt = 0; mt < 4; ++mt) {
        const int mbase = m0 + wm * 64 + mt * 16 + quad * 4;
        #pragma unroll
        for (int nt = 0; nt < 4; ++nt) {
            const int n = n0 + wn * 64 + nt * 16 + l16;
            #pragma unroll
            for (int r = 0; r < 4; ++r)
                out[(size_t)(mbase + r) * EDIM + n] = acc[mt][nt][r] + bb[nt];
        }
    }
}

extern "C" void kernel_launch(void* const* d_in, const int* in_sizes, int n_in,
                              void* d_out, int out_size, void* d_ws, size_t ws_size,
                              hipStream_t stream) {
    const float* x  = (const float*)d_in[0];
    const float* rx = (const float*)d_in[1];
    const float* w1 = (const float*)d_in[2];
    const float* b1 = (const float*)d_in[3];
    const float* w2 = (const float*)d_in[4];
    const float* b2 = (const float*)d_in[5];
    float* out = (float*)d_out;

    const int M = in_sizes[0] / EDIM;   // 16384

    ushort* w2p = (ushort*)d_ws;                                    // 2 MiB
    ushort* w1t = (ushort*)((char*)d_ws + (size_t)EDIM * FDIM * 2); // 128 KiB
    (void)ws_size; (void)n_in; (void)out_size;

    hipLaunchKernelGGL(prep, dim3(256), dim3(256), 0, stream, w2, w1, b1, w2p, w1t);
    hipLaunchKernelGGL(fused, dim3(M / BM, EDIM / BN), dim3(256), 0, stream,
                       x, rx, w1t, w2p, b2, out);
}